// Round 1
// baseline (1730.539 us; speedup 1.0000x reference)
//
#include <hip/hip_runtime.h>
#include <math.h>

#define DIM    256
#define SLOTS  8
#define NMEM   1000000
#define TILE   32
#define TPAD   260   // fp32 row pitch in LDS tile (+4 pad, keeps 16B alignment)
#define KPAD   260
#define SPAD   36    // scores/w row pitch
#define PSTRIDE 258  // per-slot partial: m, l, acc[256]

// ---------------- K1: qspace / k / rspace ----------------
// grid: SLOTS blocks x 256 threads. qspace = tanh([state|heads_s] @ qW.T + qb)
__global__ __launch_bounds__(256) void k1_query(
    const float* __restrict__ heads, const float* __restrict__ state,
    const float* __restrict__ qW, const float* __restrict__ qb,
    float* __restrict__ k_out, float* __restrict__ rspace_out) {
  __shared__ float inp[2 * DIM];
  int s = blockIdx.x, o = threadIdx.x;
  inp[o] = state[o];
  inp[DIM + o] = heads[s * DIM + o];
  __syncthreads();
  const float* w = qW + (size_t)o * (2 * DIM);
  float acc = qb[o];
#pragma unroll 8
  for (int i = 0; i < 2 * DIM; i += 4) {
    float4 wv = *(const float4*)(w + i);
    acc += wv.x * inp[i] + wv.y * inp[i + 1] + wv.z * inp[i + 2] + wv.w * inp[i + 3];
  }
  float q = tanhf(acc);
  rspace_out[s * DIM + o] = q;
  k_out[s * DIM + o] = heads[s * DIM + o] * q;
}

// ---------------- K2: fused streaming scores + online softmax + accumulate ----------------
// grid: G blocks x 256 threads; each block handles rows_per_block contiguous rows
// (rows_per_block is a multiple of TILE so chunks never overlap; OOB rows masked).
__global__ __launch_bounds__(256) void k2_stream(
    const float* __restrict__ memory, const float* __restrict__ k_in,
    float* __restrict__ partials, int rows_per_block) {
  __shared__ float tile[TILE * TPAD];       // 33.3 KB
  __shared__ float k_lds[SLOTS * KPAD];     // 8.3 KB
  __shared__ float sc_lds[SLOTS * SPAD];
  __shared__ float w_lds[SLOTS * SPAD];
  __shared__ float alpha_lds[SLOTS];

  int tid = threadIdx.x;
  for (int i = tid; i < SLOTS * DIM; i += 256)
    k_lds[(i >> 8) * KPAD + (i & 255)] = k_in[i];

  float acc[SLOTS];
#pragma unroll
  for (int s = 0; s < SLOTS; s++) acc[s] = 0.f;
  float m_st = -3.0e38f, l_st = 0.f;  // live only in threads 0..7

  int row0 = blockIdx.x * rows_per_block;
  int wave = tid >> 6, lane = tid & 63;
  int s_of = lane >> 3;                 // slot for scores phase
  int r_of = wave * 8 + (lane & 7);     // tile-row for scores phase
  __syncthreads();

  for (int t0 = 0; t0 < rows_per_block; t0 += TILE) {
    // ---- stage 32x256 fp32 tile (coalesced float4) ----
#pragma unroll
    for (int it = 0; it < (TILE * DIM) / (4 * 256); ++it) {  // 8 iters
      int idx4 = it * 256 + tid;
      int r = idx4 >> 6;
      int c = (idx4 & 63) * 4;
      int gr = row0 + t0 + r;
      float4 v = make_float4(0.f, 0.f, 0.f, 0.f);
      if (gr < NMEM) v = *(const float4*)(memory + (size_t)gr * DIM + c);
      *(float4*)(tile + r * TPAD + c) = v;
    }
    __syncthreads();

    // ---- scores: each lane computes full 256-dot for (s_of, r_of) ----
    {
      float sc = 0.f;
      const float* kk = k_lds + s_of * KPAD;
      const float* tt = tile + r_of * TPAD;
#pragma unroll 8
      for (int d = 0; d < DIM; d += 4) {
        float4 kv = *(const float4*)(kk + d);
        float4 tv = *(const float4*)(tt + d);
        sc += kv.x * tv.x + kv.y * tv.y + kv.z * tv.z + kv.w * tv.w;
      }
      int gr = row0 + t0 + r_of;
      if (gr >= NMEM) sc = -3.0e38f;   // mask OOB rows out of the softmax
      sc_lds[s_of * SPAD + r_of] = sc;
    }
    __syncthreads();

    // ---- per-slot online-softmax bookkeeping (threads 0..7) ----
    if (tid < SLOTS) {
      int s = tid;
      float tm = -3.0e38f;
      for (int r = 0; r < TILE; r++) tm = fmaxf(tm, sc_lds[s * SPAD + r]);
      float m_new = fmaxf(m_st, tm);
      float al = expf(m_st - m_new);       // exp(0)=1 in the all-masked case; scaled away at merge
      float ls = 0.f;
      for (int r = 0; r < TILE; r++) {
        float w = expf(sc_lds[s * SPAD + r] - m_new);
        w_lds[s * SPAD + r] = w;
        ls += w;
      }
      l_st = l_st * al + ls;
      m_st = m_new;
      alpha_lds[s] = al;
    }
    __syncthreads();

    // ---- accumulate: thread owns dim d=tid, 8 slots ----
    {
#pragma unroll
      for (int s = 0; s < SLOTS; s++) acc[s] *= alpha_lds[s];
      const float* tcol = tile + tid;
#pragma unroll 2
      for (int r4 = 0; r4 < TILE; r4 += 4) {
        float4 wv[SLOTS];
#pragma unroll
        for (int s = 0; s < SLOTS; s++) wv[s] = *(const float4*)(w_lds + s * SPAD + r4);
        float tv0 = tcol[(r4 + 0) * TPAD];
        float tv1 = tcol[(r4 + 1) * TPAD];
        float tv2 = tcol[(r4 + 2) * TPAD];
        float tv3 = tcol[(r4 + 3) * TPAD];
#pragma unroll
        for (int s = 0; s < SLOTS; s++)
          acc[s] += wv[s].x * tv0 + wv[s].y * tv1 + wv[s].z * tv2 + wv[s].w * tv3;
      }
    }
    __syncthreads();  // tile/w reused next iteration
  }

  // ---- write per-block partials: [G][SLOTS][m, l, acc(256)] ----
  float* pb = partials + (size_t)blockIdx.x * (SLOTS * PSTRIDE);
  if (tid < SLOTS) {
    pb[tid * PSTRIDE + 0] = m_st;
    pb[tid * PSTRIDE + 1] = l_st;
  }
#pragma unroll
  for (int s = 0; s < SLOTS; s++) pb[s * PSTRIDE + 2 + tid] = acc[s];
}

// ---------------- K3a: merge partials -> raw -> new_heads ----------------
// grid: SLOTS blocks x 256 threads
__global__ __launch_bounds__(256) void k3_merge(
    const float* __restrict__ partials, const float* __restrict__ rspace,
    const float* __restrict__ heads, float* __restrict__ new_heads, int G) {
  __shared__ float red[256];
  __shared__ float wg_lds[1024];  // G <= 1024
  int s = blockIdx.x, tid = threadIdx.x;

  float mloc = -3.0e38f;
  for (int g = tid; g < G; g += 256)
    mloc = fmaxf(mloc, partials[(size_t)g * (SLOTS * PSTRIDE) + s * PSTRIDE]);
  red[tid] = mloc;
  __syncthreads();
  for (int st = 128; st > 0; st >>= 1) {
    if (tid < st) red[tid] = fmaxf(red[tid], red[tid + st]);
    __syncthreads();
  }
  float mg = red[0];
  __syncthreads();

  float lloc = 0.f;
  for (int g = tid; g < G; g += 256) {
    const float* p = partials + (size_t)g * (SLOTS * PSTRIDE) + s * PSTRIDE;
    float w = expf(p[0] - mg);
    wg_lds[g] = w;
    lloc += w * p[1];
  }
  red[tid] = lloc;
  __syncthreads();
  for (int st = 128; st > 0; st >>= 1) {
    if (tid < st) red[tid] += red[tid + st];
    __syncthreads();
  }
  float lg = red[0];
  __syncthreads();

  float v = 0.f;
  for (int g = 0; g < G; g++)
    v += wg_lds[g] * partials[(size_t)g * (SLOTS * PSTRIDE) + s * PSTRIDE + 2 + tid];
  float raw = v / lg;
  float rs = rspace[s * DIM + tid];
  new_heads[s * DIM + tid] = raw * rs + (1.f - rs) * heads[s * DIM + tid];
}

// ---------------- K3b: new_state = [state|new_heads] @ sW.T + sb ----------------
// grid: 64 blocks x 256 threads; one wave per output row
__global__ __launch_bounds__(256) void k3b_state(
    const float* __restrict__ state, const float* __restrict__ new_heads,
    const float* __restrict__ sW, const float* __restrict__ sb,
    float* __restrict__ new_state) {
  __shared__ float cat[(SLOTS + 1) * DIM];
  int tid = threadIdx.x;
  for (int i = tid; i < (SLOTS + 1) * DIM; i += 256)
    cat[i] = (i < DIM) ? state[i] : new_heads[i - DIM];
  __syncthreads();
  int wave = tid >> 6, lane = tid & 63;
  int o = blockIdx.x * 4 + wave;
  const float* wrow = sW + (size_t)o * ((SLOTS + 1) * DIM);
  float acc = 0.f;
#pragma unroll
  for (int j = 0; j < SLOTS + 1; j++) {
    int i = j * DIM + lane * 4;
    float4 wv = *(const float4*)(wrow + i);
    float4 cv = *(const float4*)(cat + i);
    acc += wv.x * cv.x + wv.y * cv.y + wv.z * cv.z + wv.w * cv.w;
  }
  for (int off = 32; off > 0; off >>= 1) acc += __shfl_down(acc, off);
  if (lane == 0) new_state[o] = acc + sb[o];
}

// ---------------- K3c: reveal gate + output ----------------
__global__ __launch_bounds__(256) void k3c_out(
    const float* __restrict__ new_state, const float* __restrict__ rvW,
    const float* __restrict__ rvb, float* __restrict__ out) {
  __shared__ float red[256];
  int tid = threadIdx.x;
  float ns = new_state[tid];
  red[tid] = ns * rvW[tid];
  __syncthreads();
  for (int st = 128; st > 0; st >>= 1) {
    if (tid < st) red[tid] += red[tid + st];
    __syncthreads();
  }
  float reveal = 1.f / (1.f + expf(-(red[0] + rvb[0])));
  out[tid] = ns * reveal;
}

extern "C" void kernel_launch(void* const* d_in, const int* in_sizes, int n_in,
                              void* d_out, int out_size, void* d_ws, size_t ws_size,
                              hipStream_t stream) {
  const float* memory = (const float*)d_in[0];
  const float* heads  = (const float*)d_in[1];
  const float* state  = (const float*)d_in[2];
  const float* qW  = (const float*)d_in[3];
  const float* qb  = (const float*)d_in[4];
  const float* sW  = (const float*)d_in[5];
  const float* sb  = (const float*)d_in[6];
  const float* rvW = (const float*)d_in[7];
  const float* rvb = (const float*)d_in[8];
  float* out = (float*)d_out;
  float* ws  = (float*)d_ws;

  // workspace layout (floats)
  float* k_ws        = ws;          // 2048
  float* rspace_ws   = ws + 2048;   // 2048
  float* newheads_ws = ws + 4096;   // 2048
  float* newstate_ws = ws + 6144;   // 256
  float* partials    = ws + 6400;   // G * 8 * 258

  size_t avail = (ws_size / 4 > 6400) ? (ws_size / 4 - 6400) : 0;
  int G = (int)(avail / (SLOTS * PSTRIDE));
  if (G > 1024) G = 1024;
  if (G < 1) G = 1;
  // rows per block: multiple of TILE so block chunks never overlap
  int rows_per_block = ((NMEM + G * TILE - 1) / (G * TILE)) * TILE;

  k1_query<<<SLOTS, 256, 0, stream>>>(heads, state, qW, qb, k_ws, rspace_ws);
  k2_stream<<<G, 256, 0, stream>>>(memory, k_ws, partials, rows_per_block);
  k3_merge<<<SLOTS, 256, 0, stream>>>(partials, rspace_ws, heads, newheads_ws, G);
  k3b_state<<<64, 256, 0, stream>>>(state, newheads_ws, sW, sb, newstate_ws);
  k3c_out<<<1, 256, 0, stream>>>(newstate_ws, rvW, rvb, out);
}